// Round 1
// baseline (573.810 us; speedup 1.0000x reference)
//
#include <hip/hip_runtime.h>
#include <hip/hip_bf16.h>

// CC_module_H: height-axis criss-cross attention, fused per-(b,w) MFMA kernel.
// B=8, C=512, C8=64, H=W=96.

typedef __attribute__((ext_vector_type(8))) short bh8;   // 8 bf16 = one MFMA A/B frag
typedef __attribute__((ext_vector_type(4))) float fx4;   // MFMA 16x16 accum

#define MFMA16(a, b, c) __builtin_amdgcn_mfma_f32_16x16x32_bf16((a), (b), (c), 0, 0, 0)

__device__ __forceinline__ unsigned short f2bf(float f) {
  unsigned u = __float_as_uint(f);
  u += 0x7fffu + ((u >> 16) & 1u);   // RNE (finite inputs only)
  return (unsigned short)(u >> 16);
}

// ---------------- prep: weights fp32 -> bf16, MFMA-A-fragment order in ws ----
// WqkF: gt in [0,8) = 16-row tiles of [Wq;Wk] (128 rows), es in [0,16) = K-steps of 32.
//       16B chunk per lane at shorts[((gt*16+es)*64+lane)*8].
// WvF:  base 65536 shorts, ct in [0,32) over Wv's 512 rows, same scheme.
__global__ __launch_bounds__(256) void prep_w(const float* __restrict__ Wq,
                                              const float* __restrict__ Wk,
                                              const float* __restrict__ Wv,
                                              short* __restrict__ wf) {
  int tid = blockIdx.x * 256 + threadIdx.x;
  if (tid >= 40960) return;
  int lane = tid & 63;
  int es = (tid >> 6) & 15;
  int gt = tid >> 10;
  int rt = lane & 15;
  int colbase = es * 32 + (lane >> 4) * 8;
  const float* src;
  size_t dst;
  if (gt < 8) {
    int m = gt * 16 + rt;
    src = (m < 64) ? (Wq + (size_t)m * 512) : (Wk + (size_t)(m - 64) * 512);
    dst = (size_t)((gt * 16 + es) * 64 + lane) * 8;
  } else {
    int ct = gt - 8;
    src = Wv + (size_t)(ct * 16 + rt) * 512;
    dst = 65536u + (size_t)((ct * 16 + es) * 64 + lane) * 8;
  }
  bh8 v;
#pragma unroll
  for (int r = 0; r < 8; ++r) v[r] = (short)f2bf(src[colbase + r]);
  *(bh8*)(wf + dst) = v;
}

// ---------------- main fused kernel: one workgroup per (b,w) -----------------
// LDS map (bytes):
//   X   [96][512] bf16, pitch 1024, XOR swizzle byte^=((j&7)<<4)   0      .. 98304
//   ATT [96][104] bf16, pitch 208 (pad, conflict-free)             98304  .. 118272
//   Q   [96][64]  bf16, pitch 128, XOR swizzle ((i&7)<<4)          118272 .. 130560
//   K   [96][64]  bf16, pitch 128, XOR swizzle                     130560 .. 142848
//   VBLK[64][104] bf16, pitch 208 — aliases Q/K (dead after P2)    118272 .. 131584
#define XOFF 0
#define ATTOFF 98304
#define QOFF 118272
#define KOFF 130560
#define VOFF 118272
#define SMEM_BYTES 142848

__global__ __launch_bounds__(512, 2) void cc_fused(
    const float* __restrict__ x, const float* __restrict__ bq,
    const float* __restrict__ bk, const float* __restrict__ bv,
    const float* __restrict__ gamma, const short* __restrict__ wf,
    float* __restrict__ out) {
  extern __shared__ char smem[];
  const int tid = threadIdx.x;
  const int l = tid & 63, wv = tid >> 6;
  const int rl = l & 15, kg = l >> 4;
  // XCD-aware (b,w) mapping: XCD k (= bid%8) owns w in [12k, 12k+12) for all b,
  // so the 16-w cachelines of x/out are assembled within <=2 XCD L2s.
  const int bid = blockIdx.x;
  const int b = (bid >> 3) / 12;
  const int w = (bid & 7) * 12 + ((bid >> 3) % 12);
  const float g0 = gamma[0];
  const float* xb = x + (size_t)b * 4718592 + w;

  // ---- P0: gather X[j][c] = x[b,c,j,w] into LDS as bf16 (swizzled) ----
  for (int idx = tid; idx < 24576; idx += 512) {   // 96 j * 256 c-pairs
    int j = idx >> 8;
    int c = (idx & 255) * 2;
    float a0 = xb[(size_t)c * 9216 + j * 96];
    float a1 = xb[(size_t)(c + 1) * 9216 + j * 96];
    unsigned pk = (unsigned)f2bf(a0) | ((unsigned)f2bf(a1) << 16);
    *(unsigned*)(smem + XOFF + j * 1024 + ((c * 2) ^ ((j & 7) << 4))) = pk;
  }
  __syncthreads();

  // ---- P1: [q;k] = [Wq;Wk] @ X. Wave wv owns m-tile wv (16 rows of 128). ----
  {
    fx4 acc[6] = {};
    for (int es = 0; es < 16; ++es) {
      bh8 a = *(const bh8*)(wf + ((wv * 16 + es) * 64 + l) * 8);
      int kb = (es * 32 + kg * 8) * 2;
#pragma unroll
      for (int nt = 0; nt < 6; ++nt) {
        int j = nt * 16 + rl;
        bh8 bx = *(const bh8*)(smem + XOFF + j * 1024 + (kb ^ ((j & 7) << 4)));
        acc[nt] = MFMA16(a, bx, acc[nt]);
      }
    }
    const float* bp = (wv < 4) ? bq : bk;
    const int qko = (wv < 4) ? QOFF : KOFF;
    const int mb = (wv * 16) & 63;
#pragma unroll
    for (int r = 0; r < 4; ++r) {
      int ml = mb + kg * 4 + r;
      float bias = bp[ml];
#pragma unroll
      for (int nt = 0; nt < 6; ++nt) {
        int i = nt * 16 + rl;   // D: n = lane%16 (pos i), m = (lane>>4)*4+r (channel)
        *(unsigned short*)(smem + qko + i * 128 + ((ml * 2) ^ ((i & 7) << 4))) =
            f2bf(acc[nt][r] + bias);
      }
    }
  }
  __syncthreads();

  // ---- P2: energy = q^T k (i-block per wave, waves 0..5) + in-register softmax
  if (wv < 6) {
    const int i0 = wv * 16;
    fx4 e[6] = {};
#pragma unroll
    for (int ks = 0; ks < 2; ++ks) {   // K=64 channels, 2 steps of 32
      int kb = (ks * 32 + kg * 8) * 2;
      int ia = i0 + rl;
      bh8 aq = *(const bh8*)(smem + QOFF + ia * 128 + (kb ^ ((ia & 7) << 4)));
#pragma unroll
      for (int jt = 0; jt < 6; ++jt) {
        int j = jt * 16 + rl;
        bh8 bkf = *(const bh8*)(smem + KOFF + j * 128 + (kb ^ ((j & 7) << 4)));
        e[jt] = MFMA16(aq, bkf, e[jt]);
      }
    }
    // lane holds rows i = i0 + kg*4 + r, cols j = jt*16 + rl; reduce over j:
#pragma unroll
    for (int r = 0; r < 4; ++r) {
      float mx = e[0][r];
#pragma unroll
      for (int jt = 1; jt < 6; ++jt) mx = fmaxf(mx, e[jt][r]);
      mx = fmaxf(mx, __shfl_xor(mx, 1));
      mx = fmaxf(mx, __shfl_xor(mx, 2));
      mx = fmaxf(mx, __shfl_xor(mx, 4));
      mx = fmaxf(mx, __shfl_xor(mx, 8));
      float p[6], s = 0.f;
#pragma unroll
      for (int jt = 0; jt < 6; ++jt) { p[jt] = __expf(e[jt][r] - mx); s += p[jt]; }
      s += __shfl_xor(s, 1);
      s += __shfl_xor(s, 2);
      s += __shfl_xor(s, 4);
      s += __shfl_xor(s, 8);
      float inv = 1.0f / s;
      int i = i0 + kg * 4 + r;
#pragma unroll
      for (int jt = 0; jt < 6; ++jt) {
        int j = jt * 16 + rl;
        *(unsigned short*)(smem + ATTOFF + i * 208 + 2 * j) = f2bf(p[jt] * inv);
      }
    }
  }
  __syncthreads();

  // ---- P3: per 64-channel block: Vblk = Wv_blk @ X ; outT = att @ Vblk^T ----
  for (int cb = 0; cb < 8; ++cb) {
    {
      const int mt = wv >> 1, ntb = (wv & 1) * 3;   // 4 m-tiles x 6 n-tiles / 8 waves
      fx4 acc[3] = {};
      for (int es = 0; es < 16; ++es) {
        bh8 a = *(const bh8*)(wf + 65536 + (((cb * 4 + mt) * 16 + es) * 64 + l) * 8);
        int kb = (es * 32 + kg * 8) * 2;
#pragma unroll
        for (int t = 0; t < 3; ++t) {
          int j = (ntb + t) * 16 + rl;
          bh8 bx = *(const bh8*)(smem + XOFF + j * 1024 + (kb ^ ((j & 7) << 4)));
          acc[t] = MFMA16(a, bx, acc[t]);
        }
      }
#pragma unroll
      for (int t = 0; t < 3; ++t) {
        int j = (ntb + t) * 16 + rl;
#pragma unroll
        for (int r = 0; r < 4; ++r) {
          int cl = mt * 16 + kg * 4 + r;
          *(unsigned short*)(smem + VOFF + cl * 208 + 2 * j) = f2bf(acc[t][r]);
        }
      }
    }
    __syncthreads();
    {
      fx4 acc[3] = {};
      const int tg0 = wv * 3;   // 24 tiles (6 i-tiles x 4 c-tiles) / 8 waves
#pragma unroll
      for (int ks = 0; ks < 3; ++ks) {   // K=96 over j
        int jb = (ks * 32 + kg * 8) * 2;
#pragma unroll
        for (int s = 0; s < 3; ++s) {
          int it = (tg0 + s) >> 2, ct = (tg0 + s) & 3;
          bh8 a = *(const bh8*)(smem + ATTOFF + (it * 16 + rl) * 208 + jb);
          bh8 bvv = *(const bh8*)(smem + VOFF + (ct * 16 + rl) * 208 + jb);
          acc[s] = MFMA16(a, bvv, acc[s]);
        }
      }
#pragma unroll
      for (int s = 0; s < 3; ++s) {
        int it = (tg0 + s) >> 2, ct = (tg0 + s) & 3;
        int c = cb * 64 + ct * 16 + rl;
        float bvc = bv[c];   // softmax rows sum to 1 -> v-bias adds directly
        size_t base = (size_t)(b * 512 + c) * 9216 + w;
#pragma unroll
        for (int r = 0; r < 4; ++r) {
          int i = it * 16 + kg * 4 + r;
          size_t g = base + (size_t)i * 96;
          out[g] = g0 * (acc[s][r] + bvc) + x[g];
        }
      }
    }
    __syncthreads();
  }
}

extern "C" void kernel_launch(void* const* d_in, const int* in_sizes, int n_in,
                              void* d_out, int out_size, void* d_ws, size_t ws_size,
                              hipStream_t stream) {
  const float* x = (const float*)d_in[0];
  const float* Wq = (const float*)d_in[1];
  const float* bq = (const float*)d_in[2];
  const float* Wk = (const float*)d_in[3];
  const float* bk = (const float*)d_in[4];
  const float* Wv = (const float*)d_in[5];
  const float* bv = (const float*)d_in[6];
  const float* gamma = (const float*)d_in[7];
  float* out = (float*)d_out;
  short* wf = (short*)d_ws;   // 655360 bytes used

  prep_w<<<160, 256, 0, stream>>>(Wq, Wk, Wv, wf);

  hipFuncSetAttribute((const void*)cc_fused,
                      hipFuncAttributeMaxDynamicSharedMemorySize, SMEM_BYTES);
  cc_fused<<<768, 512, SMEM_BYTES, stream>>>(x, bq, bk, bv, gamma, wf, out);
}

// Round 2
// 261.864 us; speedup vs baseline: 2.1912x; 2.1912x over previous
//
#include <hip/hip_runtime.h>
#include <hip/hip_bf16.h>

// CC_module_H: height-axis criss-cross attention. B=8, C=512, C8=64, H=W=96.
// Round 2: coalesce everything — transpose-in pass (x -> xT bf16 [b,w,h,c] in
// d_out lower half), fused MFMA kernel reads xT / writes outT (d_out upper
// half; b=7 to ws), 4 ordered un-transpose+residual passes write final out.

typedef __attribute__((ext_vector_type(8))) short bh8;   // 8 bf16 = MFMA frag
typedef __attribute__((ext_vector_type(4))) float fx4;   // MFMA 16x16 accum

#define MFMA16(a, b, c) __builtin_amdgcn_mfma_f32_16x16x32_bf16((a), (b), (c), 0, 0, 0)

__device__ __forceinline__ unsigned short f2bf(float f) {
  unsigned u = __float_as_uint(f);
  u += 0x7fffu + ((u >> 16) & 1u);   // RNE (finite inputs only)
  return (unsigned short)(u >> 16);
}
__device__ __forceinline__ float bf2f(unsigned short u) {
  return __uint_as_float((unsigned)u << 16);
}

// ---------------- prep: weights fp32 -> bf16, MFMA-A-fragment order in ws ----
__global__ __launch_bounds__(256) void prep_w(const float* __restrict__ Wq,
                                              const float* __restrict__ Wk,
                                              const float* __restrict__ Wv,
                                              short* __restrict__ wf) {
  int tid = blockIdx.x * 256 + threadIdx.x;
  if (tid >= 40960) return;
  int lane = tid & 63;
  int es = (tid >> 6) & 15;
  int gt = tid >> 10;
  int rt = lane & 15;
  int colbase = es * 32 + (lane >> 4) * 8;
  const float* src;
  size_t dst;
  if (gt < 8) {
    int m = gt * 16 + rt;
    src = (m < 64) ? (Wq + (size_t)m * 512) : (Wk + (size_t)(m - 64) * 512);
    dst = (size_t)((gt * 16 + es) * 64 + lane) * 8;
  } else {
    int ct = gt - 8;
    src = Wv + (size_t)(ct * 16 + rt) * 512;
    dst = 65536u + (size_t)((ct * 16 + es) * 64 + lane) * 8;
  }
  bh8 v;
#pragma unroll
  for (int r = 0; r < 8; ++r) v[r] = (short)f2bf(src[colbase + r]);
  *(bh8*)(wf + dst) = v;
}

// ---------------- transpose-in: x[b,c,h,w] f32 -> xT[b,w,h,c] bf16 -----------
// One block per (b, h, 128-channel tile). Coalesced read along w, LDS-tile
// transpose (pitch 132 shorts = 264 B, 8B-aligned, odd dword stride-ish),
// coalesced 8B/lane write along c.
__global__ __launch_bounds__(512) void transpose_in(const float* __restrict__ x,
                                                    unsigned short* __restrict__ xT) {
  __shared__ unsigned short L[96 * 132];
  int bi = blockIdx.x;
  int ct = bi & 3;
  int hb = bi >> 2;
  int h = hb % 96;
  int b = hb / 96;
  int tid = threadIdx.x;
  const float* xs = x + ((size_t)(b * 512 + ct * 128) * 96 + h) * 96;
#pragma unroll
  for (int i = 0; i < 24; ++i) {
    int idx = tid + 512 * i;          // 128 cc x 96 w
    int cc = idx / 96, w = idx - cc * 96;
    L[w * 132 + cc] = f2bf(xs[(size_t)cc * 9216 + w]);
  }
  __syncthreads();
  unsigned short* dst = xT + ((size_t)(b * 96) * 96 + h) * 512 + ct * 128;
#pragma unroll
  for (int i = 0; i < 6; ++i) {
    int idx = tid + 512 * i;          // 96 w x 32 c-quads (8 B)
    int w = idx >> 5, ccq = idx & 31;
    *(ushort4*)(dst + (size_t)w * 49152 + ccq * 4) =
        *(const ushort4*)&L[w * 132 + ccq * 4];
  }
}

// ---------------- un-transpose + residual: out = f32(outT) + x ---------------
// One block per (b-rel, h, 128-channel tile). Coalesced outT read along c,
// LDS transpose (pitch 101 shorts = 202 B), coalesced out/x along w.
__global__ __launch_bounds__(512) void untrans(const unsigned short* __restrict__ oT,
                                               const float* __restrict__ x,
                                               float* __restrict__ out, int b0) {
  __shared__ unsigned short L[128 * 101];
  int bi = blockIdx.x;
  int ct = bi & 3;
  int hb = bi >> 2;
  int h = hb % 96;
  int brel = hb / 96;
  int b = b0 + brel;
  int tid = threadIdx.x;
  const unsigned short* src = oT + ((size_t)(brel * 96) * 96 + h) * 512 + ct * 128;
#pragma unroll
  for (int i = 0; i < 3; ++i) {
    int idx = tid + 512 * i;          // 96 w x 16 c-octs (16 B)
    int w = idx >> 4, ccb = idx & 15;
    bh8 v = *(const bh8*)(src + (size_t)w * 49152 + ccb * 8);
#pragma unroll
    for (int r = 0; r < 8; ++r) L[(ccb * 8 + r) * 101 + w] = (unsigned short)v[r];
  }
  __syncthreads();
  const float* xs = x + ((size_t)(b * 512 + ct * 128) * 96 + h) * 96;
  float* os = out + ((size_t)(b * 512 + ct * 128) * 96 + h) * 96;
#pragma unroll
  for (int i = 0; i < 24; ++i) {
    int idx = tid + 512 * i;          // 128 cc x 96 w
    int cc = idx / 96, w = idx - cc * 96;
    os[(size_t)cc * 9216 + w] = bf2f(L[cc * 101 + w]) + xs[(size_t)cc * 9216 + w];
  }
}

// ---------------- main fused kernel: one workgroup per (b,w) -----------------
// LDS map (bytes):
//   X   [96][512] bf16, pitch 1024, XOR swizzle byte^=((j&7)<<4)   0      .. 98304
//   ATT [96][104] bf16, pitch 208                                  98304  .. 118272
//   Q   [96][64]  bf16, pitch 128, XOR swizzle                     118272 .. 130560
//   K   [96][64]  bf16, pitch 128, XOR swizzle                     130560 .. 142848
//   VBLK[64][104] bf16, pitch 208 — aliases Q/K (dead after P2)    118272 .. 131584
#define XOFF 0
#define ATTOFF 98304
#define QOFF 118272
#define KOFF 130560
#define VOFF 118272
#define SMEM_BYTES 142848

// MODE 0: legacy self-contained (gather x, scattered epilogue) — ws fallback.
// MODE 1: read xT (coalesced), write outT bf16 (b<7 -> outTm, b==7 -> outT7).
template <int MODE>
__global__ __launch_bounds__(512, 2) void cc_fused(
    const float* __restrict__ x, const float* __restrict__ bq,
    const float* __restrict__ bk, const float* __restrict__ bv,
    const float* __restrict__ gamma, const short* __restrict__ wf,
    float* __restrict__ out, const unsigned short* __restrict__ xT,
    unsigned short* __restrict__ outTm, unsigned short* __restrict__ outT7) {
  extern __shared__ char smem[];
  const int tid = threadIdx.x;
  const int l = tid & 63, wv = tid >> 6;
  const int rl = l & 15, kg = l >> 4;
  const int bid = blockIdx.x;
  int b, w;
  if constexpr (MODE == 0) {
    b = (bid >> 3) / 12;
    w = (bid & 7) * 12 + ((bid >> 3) % 12);
  } else {
    b = bid / 96;
    w = bid - b * 96;
  }
  const float g0 = gamma[0];

  // ---- P0: X[j][c] into LDS as bf16 (swizzled) ----
  if constexpr (MODE == 0) {
    const float* xb = x + (size_t)b * 4718592 + w;
    for (int idx = tid; idx < 24576; idx += 512) {
      int j = idx >> 8;
      int c = (idx & 255) * 2;
      float a0 = xb[(size_t)c * 9216 + j * 96];
      float a1 = xb[(size_t)(c + 1) * 9216 + j * 96];
      unsigned pk = (unsigned)f2bf(a0) | ((unsigned)f2bf(a1) << 16);
      *(unsigned*)(smem + XOFF + j * 1024 + ((c * 2) ^ ((j & 7) << 4))) = pk;
    }
  } else {
    const unsigned short* xrow = xT + (size_t)(b * 96 + w) * 49152;
#pragma unroll
    for (int i = 0; i < 12; ++i) {
      int idx = tid + 512 * i;        // 96 j x 64 16B-chunks
      int j = idx >> 6, cb = idx & 63;
      bh8 v = *(const bh8*)(xrow + (size_t)j * 512 + cb * 8);
      *(bh8*)(smem + XOFF + j * 1024 + ((cb * 16) ^ ((j & 7) << 4))) = v;
    }
  }
  __syncthreads();

  // ---- P1: [q;k] = [Wq;Wk] @ X. Wave wv owns m-tile wv (16 rows of 128). ----
  {
    fx4 acc[6] = {};
    for (int es = 0; es < 16; ++es) {
      bh8 a = *(const bh8*)(wf + ((wv * 16 + es) * 64 + l) * 8);
      int kb = (es * 32 + kg * 8) * 2;
#pragma unroll
      for (int nt = 0; nt < 6; ++nt) {
        int j = nt * 16 + rl;
        bh8 bx = *(const bh8*)(smem + XOFF + j * 1024 + (kb ^ ((j & 7) << 4)));
        acc[nt] = MFMA16(a, bx, acc[nt]);
      }
    }
    const float* bp = (wv < 4) ? bq : bk;
    const int qko = (wv < 4) ? QOFF : KOFF;
    const int mb = (wv * 16) & 63;
#pragma unroll
    for (int r = 0; r < 4; ++r) {
      int ml = mb + kg * 4 + r;
      float bias = bp[ml];
#pragma unroll
      for (int nt = 0; nt < 6; ++nt) {
        int i = nt * 16 + rl;
        *(unsigned short*)(smem + qko + i * 128 + ((ml * 2) ^ ((i & 7) << 4))) =
            f2bf(acc[nt][r] + bias);
      }
    }
  }
  __syncthreads();

  // ---- P2: energy = q^T k + in-register softmax (waves 0..5) ----
  if (wv < 6) {
    const int i0 = wv * 16;
    fx4 e[6] = {};
#pragma unroll
    for (int ks = 0; ks < 2; ++ks) {
      int kb = (ks * 32 + kg * 8) * 2;
      int ia = i0 + rl;
      bh8 aq = *(const bh8*)(smem + QOFF + ia * 128 + (kb ^ ((ia & 7) << 4)));
#pragma unroll
      for (int jt = 0; jt < 6; ++jt) {
        int j = jt * 16 + rl;
        bh8 bkf = *(const bh8*)(smem + KOFF + j * 128 + (kb ^ ((j & 7) << 4)));
        e[jt] = MFMA16(aq, bkf, e[jt]);
      }
    }
#pragma unroll
    for (int r = 0; r < 4; ++r) {
      float mx = e[0][r];
#pragma unroll
      for (int jt = 1; jt < 6; ++jt) mx = fmaxf(mx, e[jt][r]);
      mx = fmaxf(mx, __shfl_xor(mx, 1));
      mx = fmaxf(mx, __shfl_xor(mx, 2));
      mx = fmaxf(mx, __shfl_xor(mx, 4));
      mx = fmaxf(mx, __shfl_xor(mx, 8));
      float p[6], s = 0.f;
#pragma unroll
      for (int jt = 0; jt < 6; ++jt) { p[jt] = __expf(e[jt][r] - mx); s += p[jt]; }
      s += __shfl_xor(s, 1);
      s += __shfl_xor(s, 2);
      s += __shfl_xor(s, 4);
      s += __shfl_xor(s, 8);
      float inv = 1.0f / s;
      int i = i0 + kg * 4 + r;
#pragma unroll
      for (int jt = 0; jt < 6; ++jt) {
        int j = jt * 16 + rl;
        *(unsigned short*)(smem + ATTOFF + i * 208 + 2 * j) = f2bf(p[jt] * inv);
      }
    }
  }
  __syncthreads();

  // ---- P3: per 64-channel block: Vblk = Wv_blk @ X ; outT = att @ Vblk^T ----
  unsigned short* obase = nullptr;
  if constexpr (MODE == 1)
    obase = (b < 7) ? (outTm + (size_t)b * 4718592 + (size_t)w * 49152)
                    : (outT7 + (size_t)w * 49152);
  for (int cb = 0; cb < 8; ++cb) {
    {
      const int mt = wv >> 1, ntb = (wv & 1) * 3;
      fx4 acc[3] = {};
      for (int es = 0; es < 16; ++es) {
        bh8 a = *(const bh8*)(wf + 65536 + (((cb * 4 + mt) * 16 + es) * 64 + l) * 8);
        int kb = (es * 32 + kg * 8) * 2;
#pragma unroll
        for (int t = 0; t < 3; ++t) {
          int j = (ntb + t) * 16 + rl;
          bh8 bx = *(const bh8*)(smem + XOFF + j * 1024 + (kb ^ ((j & 7) << 4)));
          acc[t] = MFMA16(a, bx, acc[t]);
        }
      }
#pragma unroll
      for (int t = 0; t < 3; ++t) {
        int j = (ntb + t) * 16 + rl;
#pragma unroll
        for (int r = 0; r < 4; ++r) {
          int cl = mt * 16 + kg * 4 + r;
          *(unsigned short*)(smem + VOFF + cl * 208 + 2 * j) = f2bf(acc[t][r]);
        }
      }
    }
    __syncthreads();
    {
      fx4 acc[3] = {};
      const int tg0 = wv * 3;
#pragma unroll
      for (int ks = 0; ks < 3; ++ks) {
        int jb = (ks * 32 + kg * 8) * 2;
#pragma unroll
        for (int s = 0; s < 3; ++s) {
          int it = (tg0 + s) >> 2, ct = (tg0 + s) & 3;
          bh8 a = *(const bh8*)(smem + ATTOFF + (it * 16 + rl) * 208 + jb);
          bh8 bvv = *(const bh8*)(smem + VOFF + (ct * 16 + rl) * 208 + jb);
          acc[s] = MFMA16(a, bvv, acc[s]);
        }
      }
#pragma unroll
      for (int s = 0; s < 3; ++s) {
        int it = (tg0 + s) >> 2, ct = (tg0 + s) & 3;
        int c = cb * 64 + ct * 16 + rl;
        float bvc = bv[c];
        if constexpr (MODE == 0) {
          size_t base = (size_t)(b * 512 + c) * 9216 + w;
#pragma unroll
          for (int r = 0; r < 4; ++r) {
            int i = it * 16 + kg * 4 + r;
            size_t g = base + (size_t)i * 96;
            out[g] = g0 * (acc[s][r] + bvc) + x[g];
          }
        } else {
#pragma unroll
          for (int r = 0; r < 4; ++r) {
            int i = it * 16 + kg * 4 + r;
            obase[(size_t)i * 512 + c] = f2bf(g0 * (acc[s][r] + bvc));
          }
        }
      }
    }
    __syncthreads();
  }
}

extern "C" void kernel_launch(void* const* d_in, const int* in_sizes, int n_in,
                              void* d_out, int out_size, void* d_ws, size_t ws_size,
                              hipStream_t stream) {
  const float* x = (const float*)d_in[0];
  const float* Wq = (const float*)d_in[1];
  const float* bq = (const float*)d_in[2];
  const float* Wk = (const float*)d_in[3];
  const float* bk = (const float*)d_in[4];
  const float* Wv = (const float*)d_in[5];
  const float* bv = (const float*)d_in[6];
  const float* gamma = (const float*)d_in[7];
  float* out = (float*)d_out;
  short* wf = (short*)d_ws;                    // 655,360 B weights

  prep_w<<<160, 256, 0, stream>>>(Wq, Wk, Wv, wf);

  const size_t WS_NEED = 1048576u + 9437184u;  // outT(b=7) at ws+1MB
  if (ws_size >= WS_NEED) {
    unsigned short* xT = (unsigned short*)d_out;                         // 75.5 MB
    unsigned short* outTm = (unsigned short*)((char*)d_out + 75497472);  // b 0..6
    unsigned short* outT7 = (unsigned short*)((char*)d_ws + 1048576);    // b 7

    transpose_in<<<3072, 512, 0, stream>>>(x, xT);

    hipFuncSetAttribute((const void*)cc_fused<1>,
                        hipFuncAttributeMaxDynamicSharedMemorySize, SMEM_BYTES);
    cc_fused<1><<<768, 512, SMEM_BYTES, stream>>>(x, bq, bk, bv, gamma,
                                                  (const short*)wf, out, xT,
                                                  outTm, outT7);
    // Ordered un-transpose passes: each launch only overwrites outT regions
    // consumed by the previous launch (range proof in source comments).
    untrans<<<1536, 512, 0, stream>>>(outTm, x, out, 0);                       // b0..3
    untrans<<<768, 512, 0, stream>>>(outTm + (size_t)4 * 4718592, x, out, 4);  // b4,5
    untrans<<<384, 512, 0, stream>>>(outTm + (size_t)6 * 4718592, x, out, 6);  // b6
    untrans<<<384, 512, 0, stream>>>(outT7, x, out, 7);                        // b7
  } else {
    hipFuncSetAttribute((const void*)cc_fused<0>,
                        hipFuncAttributeMaxDynamicSharedMemorySize, SMEM_BYTES);
    cc_fused<0><<<768, 512, SMEM_BYTES, stream>>>(x, bq, bk, bv, gamma,
                                                  (const short*)wf, out,
                                                  nullptr, nullptr, nullptr);
  }
}

// Round 3
// 255.285 us; speedup vs baseline: 2.2477x; 1.0258x over previous
//
#include <hip/hip_runtime.h>
#include <hip/hip_bf16.h>

// CC_module_H: height-axis criss-cross attention. B=8, C=512, C8=64, H=W=96.
// Round 3: fused kernel restructured for in-wave MFMA operand reuse
// (P1: 2mt x 3nt, Vblk: 4mt x 3nt over 256-channel blocks) + fp8 att/V for
// the PV stage (2 cb iterations, 7 barriers instead of 19).

typedef __attribute__((ext_vector_type(8))) short bh8;   // 8 bf16 = MFMA frag
typedef __attribute__((ext_vector_type(4))) float fx4;   // MFMA 16x16 accum

#define MFMA16(a, b, c) __builtin_amdgcn_mfma_f32_16x16x32_bf16((a), (b), (c), 0, 0, 0)
#define MFMA8(a, b, c) __builtin_amdgcn_mfma_f32_16x16x32_fp8_fp8((a), (b), (c), 0, 0, 0)

__device__ __forceinline__ unsigned short f2bf(float f) {
  unsigned u = __float_as_uint(f);
  u += 0x7fffu + ((u >> 16) & 1u);   // RNE (finite inputs only)
  return (unsigned short)(u >> 16);
}
__device__ __forceinline__ float bf2f(unsigned short u) {
  return __uint_as_float((unsigned)u << 16);
}
// OCP e4m3fn encode, RNE (bias 7, denorm grid 2^-9, max 448, no inf).
__device__ __forceinline__ unsigned char f2e4m3(float f) {
  unsigned b = __float_as_uint(f);
  unsigned s = (b >> 24) & 0x80u;
  unsigned a = b & 0x7fffffffu;
  float af = __uint_as_float(a);
  if (af >= 448.f) return (unsigned char)(s | 0x7e);
  if (af < 0.015625f) {                       // below min normal 2^-6
    int n = (int)(af * 512.0f + 0.5f);        // denormal: round(a*2^9), n<=8
    return (unsigned char)(s | (unsigned)n);
  }
  a += 0x7ffffu + ((a >> 20) & 1u);           // RNE keeping top 3 mantissa bits
  unsigned E = a >> 23, M = (a >> 20) & 7u;
  if (E >= 136u) return (unsigned char)(s | 0x7e);
  return (unsigned char)(s | ((E - 120u) << 3) | M);
}

// ---------------- prep: weights fp32 -> bf16, MFMA-A-fragment order in ws ----
__global__ __launch_bounds__(256) void prep_w(const float* __restrict__ Wq,
                                              const float* __restrict__ Wk,
                                              const float* __restrict__ Wv,
                                              short* __restrict__ wf) {
  int tid = blockIdx.x * 256 + threadIdx.x;
  if (tid >= 40960) return;
  int lane = tid & 63;
  int es = (tid >> 6) & 15;
  int gt = tid >> 10;
  int rt = lane & 15;
  int colbase = es * 32 + (lane >> 4) * 8;
  const float* src;
  size_t dst;
  if (gt < 8) {
    int m = gt * 16 + rt;
    src = (m < 64) ? (Wq + (size_t)m * 512) : (Wk + (size_t)(m - 64) * 512);
    dst = (size_t)((gt * 16 + es) * 64 + lane) * 8;
  } else {
    int ct = gt - 8;
    src = Wv + (size_t)(ct * 16 + rt) * 512;
    dst = 65536u + (size_t)((ct * 16 + es) * 64 + lane) * 8;
  }
  bh8 v;
#pragma unroll
  for (int r = 0; r < 8; ++r) v[r] = (short)f2bf(src[colbase + r]);
  *(bh8*)(wf + dst) = v;
}

// ---------------- transpose-in: x[b,c,h,w] f32 -> xT[b,w,h,c] bf16 -----------
__global__ __launch_bounds__(512) void transpose_in(const float* __restrict__ x,
                                                    unsigned short* __restrict__ xT) {
  __shared__ unsigned short L[96 * 132];
  int bi = blockIdx.x;
  int ct = bi & 3;
  int hb = bi >> 2;
  int h = hb % 96;
  int b = hb / 96;
  int tid = threadIdx.x;
  const float* xs = x + ((size_t)(b * 512 + ct * 128) * 96 + h) * 96;
#pragma unroll
  for (int i = 0; i < 24; ++i) {
    int idx = tid + 512 * i;          // 128 cc x 96 w
    int cc = idx / 96, w = idx - cc * 96;
    L[w * 132 + cc] = f2bf(xs[(size_t)cc * 9216 + w]);
  }
  __syncthreads();
  unsigned short* dst = xT + ((size_t)(b * 96) * 96 + h) * 512 + ct * 128;
#pragma unroll
  for (int i = 0; i < 6; ++i) {
    int idx = tid + 512 * i;          // 96 w x 32 c-quads (8 B)
    int w = idx >> 5, ccq = idx & 31;
    *(ushort4*)(dst + (size_t)w * 49152 + ccq * 4) =
        *(const ushort4*)&L[w * 132 + ccq * 4];
  }
}

// ---------------- un-transpose + residual: out = f32(outT) + x ---------------
__global__ __launch_bounds__(512) void untrans(const unsigned short* __restrict__ oT,
                                               const float* __restrict__ x,
                                               float* __restrict__ out, int b0) {
  __shared__ unsigned short L[128 * 101];
  int bi = blockIdx.x;
  int ct = bi & 3;
  int hb = bi >> 2;
  int h = hb % 96;
  int brel = hb / 96;
  int b = b0 + brel;
  int tid = threadIdx.x;
  const unsigned short* src = oT + ((size_t)(brel * 96) * 96 + h) * 512 + ct * 128;
#pragma unroll
  for (int i = 0; i < 3; ++i) {
    int idx = tid + 512 * i;          // 96 w x 16 c-octs (16 B)
    int w = idx >> 4, ccb = idx & 15;
    bh8 v = *(const bh8*)(src + (size_t)w * 49152 + ccb * 8);
#pragma unroll
    for (int r = 0; r < 8; ++r) L[(ccb * 8 + r) * 101 + w] = (unsigned short)v[r];
  }
  __syncthreads();
  const float* xs = x + ((size_t)(b * 512 + ct * 128) * 96 + h) * 96;
  float* os = out + ((size_t)(b * 512 + ct * 128) * 96 + h) * 96;
#pragma unroll
  for (int i = 0; i < 24; ++i) {
    int idx = tid + 512 * i;          // 128 cc x 96 w
    int cc = idx / 96, w = idx - cc * 96;
    os[(size_t)cc * 9216 + w] = bf2f(L[cc * 101 + w]) + xs[(size_t)cc * 9216 + w];
  }
}

// ---------------- main fused kernel (round 3): one wg per (b,w) --------------
// LDS map (bytes):
//   X    [96][512] bf16, pitch 1024, XOR swizzle byte^=((j&7)<<4)  0      .. 98304
//   ATT8 [96][104] fp8                                             98304  .. 108288
//   Q    [96][64]  bf16, pitch 128, XOR swizzle                    108288 .. 120576
//   K    [96][64]  bf16, pitch 128, XOR swizzle                    120576 .. 132864
//   V8   [256][104] fp8 — aliases Q/K (dead after P2)              108288 .. 134912
#define XOFF2 0
#define ATT8 98304
#define QOFF2 108288
#define KOFF2 120576
#define V8OFF 108288
#define SMEM2 134912

__global__ __launch_bounds__(512, 2) void cc_fused2(
    const float* __restrict__ bq, const float* __restrict__ bk,
    const float* __restrict__ bv, const float* __restrict__ gamma,
    const short* __restrict__ wf, const unsigned short* __restrict__ xT,
    unsigned short* __restrict__ outTm, unsigned short* __restrict__ outT7) {
  extern __shared__ char smem[];
  const int tid = threadIdx.x;
  const int l = tid & 63, wv = tid >> 6;
  const int rl = l & 15, kg = l >> 4;
  const int bid = blockIdx.x;
  const int b = bid / 96;
  const int w = bid - b * 96;
  const float g0 = gamma[0];

  // ---- P0: X[j][c] into LDS as bf16 (swizzled), coalesced from xT ----
  {
    const unsigned short* xrow = xT + (size_t)(b * 96 + w) * 49152;
#pragma unroll
    for (int i = 0; i < 12; ++i) {
      int idx = tid + 512 * i;        // 96 j x 64 16B-chunks
      int j = idx >> 6, cb = idx & 63;
      bh8 v = *(const bh8*)(xrow + (size_t)j * 512 + cb * 8);
      *(bh8*)(smem + XOFF2 + j * 1024 + ((cb * 16) ^ ((j & 7) << 4))) = v;
    }
  }
  __syncthreads();

  // ---- P1: [q;k] = [Wq;Wk] @ X. Wave role: mg=wv>>1 (mt 2mg,2mg+1),
  //      ng=wv&1 (nt 3ng..3ng+2). In-wave B-reuse across 2 m-tiles. ----
  {
    const int mg = wv >> 1, ng = wv & 1;
    fx4 acc[2][3] = {};
    for (int es = 0; es < 16; ++es) {
      bh8 a0 = *(const bh8*)(wf + (((2 * mg + 0) * 16 + es) * 64 + l) * 8);
      bh8 a1 = *(const bh8*)(wf + (((2 * mg + 1) * 16 + es) * 64 + l) * 8);
      int kb = es * 64 + kg * 16;
#pragma unroll
      for (int t = 0; t < 3; ++t) {
        int j = (3 * ng + t) * 16 + rl;
        bh8 bx = *(const bh8*)(smem + XOFF2 + j * 1024 + (kb ^ ((j & 7) << 4)));
        acc[0][t] = MFMA16(a0, bx, acc[0][t]);
        acc[1][t] = MFMA16(a1, bx, acc[1][t]);
      }
    }
#pragma unroll
    for (int p = 0; p < 2; ++p) {
      int base = (2 * mg + p) * 16;
      const float* bp = (base < 64) ? bq : bk;
      const int qko = (base < 64) ? QOFF2 : KOFF2;
      const int mb = base & 63;
#pragma unroll
      for (int r = 0; r < 4; ++r) {
        int ml = mb + kg * 4 + r;
        float bias = bp[ml];
#pragma unroll
        for (int t = 0; t < 3; ++t) {
          int i = (3 * ng + t) * 16 + rl;
          *(unsigned short*)(smem + qko + i * 128 + ((ml * 2) ^ ((i & 7) << 4))) =
              f2bf(acc[p][t][r] + bias);
        }
      }
    }
  }
  __syncthreads();

  // ---- P2: energy = q^T k + in-register softmax (waves 0..5); att -> fp8 ----
  if (wv < 6) {
    const int i0 = wv * 16;
    fx4 e[6] = {};
#pragma unroll
    for (int ks = 0; ks < 2; ++ks) {
      int kb = (ks * 32 + kg * 8) * 2;
      int ia = i0 + rl;
      bh8 aq = *(const bh8*)(smem + QOFF2 + ia * 128 + (kb ^ ((ia & 7) << 4)));
#pragma unroll
      for (int jt = 0; jt < 6; ++jt) {
        int j = jt * 16 + rl;
        bh8 bkf = *(const bh8*)(smem + KOFF2 + j * 128 + (kb ^ ((j & 7) << 4)));
        e[jt] = MFMA16(aq, bkf, e[jt]);
      }
    }
#pragma unroll
    for (int r = 0; r < 4; ++r) {
      float mx = e[0][r];
#pragma unroll
      for (int jt = 1; jt < 6; ++jt) mx = fmaxf(mx, e[jt][r]);
      mx = fmaxf(mx, __shfl_xor(mx, 1));
      mx = fmaxf(mx, __shfl_xor(mx, 2));
      mx = fmaxf(mx, __shfl_xor(mx, 4));
      mx = fmaxf(mx, __shfl_xor(mx, 8));
      float p[6], s = 0.f;
#pragma unroll
      for (int jt = 0; jt < 6; ++jt) { p[jt] = __expf(e[jt][r] - mx); s += p[jt]; }
      s += __shfl_xor(s, 1);
      s += __shfl_xor(s, 2);
      s += __shfl_xor(s, 4);
      s += __shfl_xor(s, 8);
      float inv = 1.0f / s;
      int i = i0 + kg * 4 + r;
#pragma unroll
      for (int jt = 0; jt < 6; ++jt) {
        int j = jt * 16 + rl;
        *(unsigned char*)(smem + ATT8 + i * 104 + j) = f2e4m3(p[jt] * inv);
      }
    }
  }
  __syncthreads();

  // ---- P3: 2 blocks of 256 channels: V8 = fp8(Wv_blk @ X); out = att @ V ----
  unsigned short* obase = (b < 7)
      ? (outTm + (size_t)b * 4718592 + (size_t)w * 49152)
      : (outT7 + (size_t)w * 49152);
  for (int cb = 0; cb < 2; ++cb) {
    {   // Vblk: wave role mg=wv>>1 (4 m-tiles), ng=wv&1 (3 n-tiles)
      const int mg = wv >> 1, ng = wv & 1;
      fx4 vac[4][3] = {};
      for (int es = 0; es < 16; ++es) {
        bh8 a[4];
#pragma unroll
        for (int q = 0; q < 4; ++q)
          a[q] = *(const bh8*)(wf + 65536 +
                               (((cb * 16 + mg * 4 + q) * 16 + es) * 64 + l) * 8);
        int kb = es * 64 + kg * 16;
#pragma unroll
        for (int t = 0; t < 3; ++t) {
          int j = (3 * ng + t) * 16 + rl;
          bh8 bx = *(const bh8*)(smem + XOFF2 + j * 1024 + (kb ^ ((j & 7) << 4)));
#pragma unroll
          for (int q = 0; q < 4; ++q) vac[q][t] = MFMA16(a[q], bx, vac[q][t]);
        }
      }
#pragma unroll
      for (int q = 0; q < 4; ++q)
#pragma unroll
        for (int t = 0; t < 3; ++t) {
          int j = (3 * ng + t) * 16 + rl;
#pragma unroll
          for (int r = 0; r < 4; ++r) {
            int cl = (mg * 4 + q) * 16 + kg * 4 + r;
            *(unsigned char*)(smem + V8OFF + cl * 104 + j) = f2e4m3(vac[q][t][r]);
          }
        }
    }
    __syncthreads();
    {   // PV (fp8 x fp8): wave role ig=wv&1 (3 i-tiles), cg=wv>>1 (4 c-tiles)
      const int ig = wv & 1, cg = wv >> 1;
      fx4 pac[3][4] = {};
#pragma unroll
      for (int ks = 0; ks < 3; ++ks) {
        int jb = ks * 32 + kg * 8;
        long aa[3], bb[4];
#pragma unroll
        for (int s = 0; s < 3; ++s)
          aa[s] = *(const long*)(smem + ATT8 + ((ig * 3 + s) * 16 + rl) * 104 + jb);
#pragma unroll
        for (int u = 0; u < 4; ++u)
          bb[u] = *(const long*)(smem + V8OFF + ((cg * 4 + u) * 16 + rl) * 104 + jb);
#pragma unroll
        for (int s = 0; s < 3; ++s)
#pragma unroll
          for (int u = 0; u < 4; ++u) pac[s][u] = MFMA8(aa[s], bb[u], pac[s][u]);
      }
#pragma unroll
      for (int s = 0; s < 3; ++s)
#pragma unroll
        for (int u = 0; u < 4; ++u) {
          int it = ig * 3 + s, ct = cg * 4 + u;
          int c = cb * 256 + ct * 16 + rl;
          float bvc = bv[c];   // softmax rows sum to 1 -> v-bias adds directly
#pragma unroll
          for (int r = 0; r < 4; ++r) {
            int i = it * 16 + kg * 4 + r;
            obase[(size_t)i * 512 + c] = f2bf(g0 * (pac[s][u][r] + bvc));
          }
        }
    }
    __syncthreads();
  }
}

// ---------------- legacy self-contained fallback (round-1 proven) ------------
__global__ __launch_bounds__(512, 2) void cc_fused_legacy(
    const float* __restrict__ x, const float* __restrict__ bq,
    const float* __restrict__ bk, const float* __restrict__ bv,
    const float* __restrict__ gamma, const short* __restrict__ wf,
    float* __restrict__ out) {
  extern __shared__ char smem[];
  const int tid = threadIdx.x;
  const int l = tid & 63, wv = tid >> 6;
  const int rl = l & 15, kg = l >> 4;
  const int bid = blockIdx.x;
  const int b = (bid >> 3) / 12;
  const int w = (bid & 7) * 12 + ((bid >> 3) % 12);
  const float g0 = gamma[0];
  const float* xb = x + (size_t)b * 4718592 + w;
  for (int idx = tid; idx < 24576; idx += 512) {
    int j = idx >> 8;
    int c = (idx & 255) * 2;
    float a0 = xb[(size_t)c * 9216 + j * 96];
    float a1 = xb[(size_t)(c + 1) * 9216 + j * 96];
    unsigned pk = (unsigned)f2bf(a0) | ((unsigned)f2bf(a1) << 16);
    *(unsigned*)(smem + j * 1024 + ((c * 2) ^ ((j & 7) << 4))) = pk;
  }
  __syncthreads();
  {
    fx4 acc[6] = {};
    for (int es = 0; es < 16; ++es) {
      bh8 a = *(const bh8*)(wf + ((wv * 16 + es) * 64 + l) * 8);
      int kb = (es * 32 + kg * 8) * 2;
#pragma unroll
      for (int nt = 0; nt < 6; ++nt) {
        int j = nt * 16 + rl;
        bh8 bx = *(const bh8*)(smem + j * 1024 + (kb ^ ((j & 7) << 4)));
        acc[nt] = MFMA16(a, bx, acc[nt]);
      }
    }
    const float* bp = (wv < 4) ? bq : bk;
    const int qko = (wv < 4) ? 118272 : 130560;
    const int mb = (wv * 16) & 63;
#pragma unroll
    for (int r = 0; r < 4; ++r) {
      int ml = mb + kg * 4 + r;
      float bias = bp[ml];
#pragma unroll
      for (int nt = 0; nt < 6; ++nt) {
        int i = nt * 16 + rl;
        *(unsigned short*)(smem + qko + i * 128 + ((ml * 2) ^ ((i & 7) << 4))) =
            f2bf(acc[nt][r] + bias);
      }
    }
  }
  __syncthreads();
  if (wv < 6) {
    const int i0 = wv * 16;
    fx4 e[6] = {};
#pragma unroll
    for (int ks = 0; ks < 2; ++ks) {
      int kb = (ks * 32 + kg * 8) * 2;
      int ia = i0 + rl;
      bh8 aq = *(const bh8*)(smem + 118272 + ia * 128 + (kb ^ ((ia & 7) << 4)));
#pragma unroll
      for (int jt = 0; jt < 6; ++jt) {
        int j = jt * 16 + rl;
        bh8 bkf = *(const bh8*)(smem + 130560 + j * 128 + (kb ^ ((j & 7) << 4)));
        e[jt] = MFMA16(aq, bkf, e[jt]);
      }
    }
#pragma unroll
    for (int r = 0; r < 4; ++r) {
      float mx = e[0][r];
#pragma unroll
      for (int jt = 1; jt < 6; ++jt) mx = fmaxf(mx, e[jt][r]);
      mx = fmaxf(mx, __shfl_xor(mx, 1));
      mx = fmaxf(mx, __shfl_xor(mx, 2));
      mx = fmaxf(mx, __shfl_xor(mx, 4));
      mx = fmaxf(mx, __shfl_xor(mx, 8));
      float p[6], s = 0.f;
#pragma unroll
      for (int jt = 0; jt < 6; ++jt) { p[jt] = __expf(e[jt][r] - mx); s += p[jt]; }
      s += __shfl_xor(s, 1);
      s += __shfl_xor(s, 2);
      s += __shfl_xor(s, 4);
      s += __shfl_xor(s, 8);
      float inv = 1.0f / s;
      int i = i0 + kg * 4 + r;
#pragma unroll
      for (int jt = 0; jt < 6; ++jt) {
        int j = jt * 16 + rl;
        *(unsigned short*)(smem + 98304 + i * 208 + 2 * j) = f2bf(p[jt] * inv);
      }
    }
  }
  __syncthreads();
  for (int cb = 0; cb < 8; ++cb) {
    {
      const int mt = wv >> 1, ntb = (wv & 1) * 3;
      fx4 acc[3] = {};
      for (int es = 0; es < 16; ++es) {
        bh8 a = *(const bh8*)(wf + 65536 + (((cb * 4 + mt) * 16 + es) * 64 + l) * 8);
        int kb = (es * 32 + kg * 8) * 2;
#pragma unroll
        for (int t = 0; t < 3; ++t) {
          int j = (ntb + t) * 16 + rl;
          bh8 bx = *(const bh8*)(smem + j * 1024 + (kb ^ ((j & 7) << 4)));
          acc[t] = MFMA16(a, bx, acc[t]);
        }
      }
#pragma unroll
      for (int t = 0; t < 3; ++t) {
        int j = (ntb + t) * 16 + rl;
#pragma unroll
        for (int r = 0; r < 4; ++r) {
          int cl = mt * 16 + kg * 4 + r;
          *(unsigned short*)(smem + 118272 + cl * 208 + 2 * j) = f2bf(acc[t][r]);
        }
      }
    }
    __syncthreads();
    {
      fx4 acc[3] = {};
      const int tg0 = wv * 3;
#pragma unroll
      for (int ks = 0; ks < 3; ++ks) {
        int jb = (ks * 32 + kg * 8) * 2;
#pragma unroll
        for (int s = 0; s < 3; ++s) {
          int it = (tg0 + s) >> 2, ct = (tg0 + s) & 3;
          bh8 a = *(const bh8*)(smem + 98304 + (it * 16 + rl) * 208 + jb);
          bh8 bvv = *(const bh8*)(smem + 118272 + (ct * 16 + rl) * 208 + jb);
          acc[s] = MFMA16(a, bvv, acc[s]);
        }
      }
#pragma unroll
      for (int s = 0; s < 3; ++s) {
        int it = (tg0 + s) >> 2, ct = (tg0 + s) & 3;
        int c = cb * 64 + ct * 16 + rl;
        float bvc = bv[c];
        size_t base = (size_t)(b * 512 + c) * 9216 + w;
#pragma unroll
        for (int r = 0; r < 4; ++r) {
          int i = it * 16 + kg * 4 + r;
          size_t g = base + (size_t)i * 96;
          out[g] = g0 * (acc[s][r] + bvc) + x[g];
        }
      }
    }
    __syncthreads();
  }
}

extern "C" void kernel_launch(void* const* d_in, const int* in_sizes, int n_in,
                              void* d_out, int out_size, void* d_ws, size_t ws_size,
                              hipStream_t stream) {
  const float* x = (const float*)d_in[0];
  const float* Wq = (const float*)d_in[1];
  const float* bq = (const float*)d_in[2];
  const float* Wk = (const float*)d_in[3];
  const float* bk = (const float*)d_in[4];
  const float* Wv = (const float*)d_in[5];
  const float* bv = (const float*)d_in[6];
  const float* gamma = (const float*)d_in[7];
  float* out = (float*)d_out;
  short* wf = (short*)d_ws;                    // 655,360 B weights

  prep_w<<<160, 256, 0, stream>>>(Wq, Wk, Wv, wf);

  const size_t WS_NEED = 1048576u + 9437184u;  // outT(b=7) at ws+1MB
  if (ws_size >= WS_NEED) {
    unsigned short* xT = (unsigned short*)d_out;                         // 72 MiB
    unsigned short* outTm = (unsigned short*)((char*)d_out + 75497472);  // b 0..6
    unsigned short* outT7 = (unsigned short*)((char*)d_ws + 1048576);    // b 7

    transpose_in<<<3072, 512, 0, stream>>>(x, xT);

    hipFuncSetAttribute((const void*)cc_fused2,
                        hipFuncAttributeMaxDynamicSharedMemorySize, SMEM2);
    cc_fused2<<<768, 512, SMEM2, stream>>>(bq, bk, bv, gamma, (const short*)wf,
                                           xT, outTm, outT7);
    // Ordered un-transpose passes: each launch only overwrites outT regions
    // consumed by the previous launch (range proof per round 2).
    untrans<<<1536, 512, 0, stream>>>(outTm, x, out, 0);                       // b0..3
    untrans<<<768, 512, 0, stream>>>(outTm + (size_t)4 * 4718592, x, out, 4);  // b4,5
    untrans<<<384, 512, 0, stream>>>(outTm + (size_t)6 * 4718592, x, out, 6);  // b6
    untrans<<<384, 512, 0, stream>>>(outT7, x, out, 7);                        // b7
  } else {
    hipFuncSetAttribute((const void*)cc_fused_legacy,
                        hipFuncAttributeMaxDynamicSharedMemorySize, 142848);
    cc_fused_legacy<<<768, 512, 142848, stream>>>(x, bq, bk, bv, gamma,
                                                  (const short*)wf, out);
  }
}